// Round 1
// baseline (883.827 us; speedup 1.0000x reference)
//
#include <hip/hip_runtime.h>

#define TT 65536          // tokens
#define DM 512            // d_model
#define DFF 2048          // d_ff
#define NE 8              // experts
#define CAP 10240         // capacity per expert
#define NCHUNK (TT / 64)  // 1024 chunks of 64 tokens

typedef __attribute__((ext_vector_type(8))) short bf16x8;
typedef __attribute__((ext_vector_type(4))) float f32x4;

// RTNE f32 -> bf16 (no NaN inputs in this problem)
__device__ __forceinline__ unsigned short f2bf(float f) {
  unsigned u = __float_as_uint(f);
  unsigned r = (u + 0x7fffu + ((u >> 16) & 1u)) >> 16;
  return (unsigned short)r;
}

__device__ __forceinline__ void gll16(const void* g, void* l) {
  __builtin_amdgcn_global_load_lds((const __attribute__((address_space(1))) void*)g,
                                   (__attribute__((address_space(3))) void*)l, 16, 0, 0);
}

// ---------------- weight f32 -> bf16 conversion ----------------
__global__ __launch_bounds__(256) void convw_kernel(
    const float* __restrict__ Wi, const float* __restrict__ Wo,
    unsigned short* __restrict__ WiB, unsigned short* __restrict__ WoB) {
  const int n4 = NE * DFF * DM / 4;
  for (int i = blockIdx.x * blockDim.x + threadIdx.x; i < n4;
       i += gridDim.x * blockDim.x) {
    float4 a = ((const float4*)Wi)[i];
    ushort4 oa;
    oa.x = f2bf(a.x); oa.y = f2bf(a.y); oa.z = f2bf(a.z); oa.w = f2bf(a.w);
    ((ushort4*)WiB)[i] = oa;
    float4 b = ((const float4*)Wo)[i];
    ushort4 ob;
    ob.x = f2bf(b.x); ob.y = f2bf(b.y); ob.z = f2bf(b.z); ob.w = f2bf(b.w);
    ((ushort4*)WoB)[i] = ob;
  }
}

// ---------------- router: f64 logits, softmax, argmax, histograms ----------------
// grid 256 blocks x 256 thr; wave w handles chunk = blockIdx.x*4+w (64 tokens)
__global__ __launch_bounds__(256) void router_kernel(
    const float* __restrict__ x, const float* __restrict__ Wr,
    const float* __restrict__ br, float* __restrict__ probs_out,
    float* __restrict__ top1_out, int* __restrict__ eid,
    int* __restrict__ chunkHist, float* __restrict__ probsum,
    unsigned short* __restrict__ xbf) {
  __shared__ float wls[NE * DM];  // 16 KB
  int tid = threadIdx.x;
  for (int i = tid; i < NE * DM; i += 256) wls[i] = Wr[i];
  __syncthreads();
  int wv = tid >> 6, ln = tid & 63;
  int chunk = blockIdx.x * 4 + wv;
  int t0 = chunk * 64;
  float bb[NE];
#pragma unroll
  for (int e = 0; e < NE; ++e) bb[e] = br[e];
  float psum[NE];
#pragma unroll
  for (int e = 0; e < NE; ++e) psum[e] = 0.f;
  int hcnt = 0;
  for (int it = 0; it < 64; ++it) {
    int t = t0 + it;
    const float4* xr = (const float4*)(x + (size_t)t * DM);
    float4 v0 = xr[ln * 2], v1 = xr[ln * 2 + 1];
    // bf16 copy of x for the FFN stage
    uint4 pk;
    pk.x = (unsigned)f2bf(v0.x) | ((unsigned)f2bf(v0.y) << 16);
    pk.y = (unsigned)f2bf(v0.z) | ((unsigned)f2bf(v0.w) << 16);
    pk.z = (unsigned)f2bf(v1.x) | ((unsigned)f2bf(v1.y) << 16);
    pk.w = (unsigned)f2bf(v1.z) | ((unsigned)f2bf(v1.w) << 16);
    *(uint4*)(xbf + (size_t)t * DM + ln * 8) = pk;
    double acc[NE];
#pragma unroll
    for (int e = 0; e < NE; ++e) {
      const float* w = wls + e * DM + ln * 8;
      double a = 0.0;
      a += (double)v0.x * (double)w[0];
      a += (double)v0.y * (double)w[1];
      a += (double)v0.z * (double)w[2];
      a += (double)v0.w * (double)w[3];
      a += (double)v1.x * (double)w[4];
      a += (double)v1.y * (double)w[5];
      a += (double)v1.z * (double)w[6];
      a += (double)v1.w * (double)w[7];
      acc[e] = a;
    }
#pragma unroll
    for (int e = 0; e < NE; ++e) {
#pragma unroll
      for (int off = 32; off > 0; off >>= 1) acc[e] += __shfl_xor(acc[e], off, 64);
    }
    double l[NE];
#pragma unroll
    for (int e = 0; e < NE; ++e) l[e] = acc[e] + (double)bb[e];
    double best = l[0];
    int amax = 0;
#pragma unroll
    for (int e = 1; e < NE; ++e)
      if (l[e] > best) { best = l[e]; amax = e; }
    float fe[NE];
    float s = 0.f;
#pragma unroll
    for (int e = 0; e < NE; ++e) { fe[e] = expf((float)(l[e] - best)); s += fe[e]; }
    float inv = 1.0f / s;
#pragma unroll
    for (int e = 0; e < NE; ++e) psum[e] += fe[e] * inv;
    hcnt += ((ln < 8) && (amax == ln)) ? 1 : 0;
    if (ln == 0) {
      *(float4*)(probs_out + (size_t)t * 8) =
          make_float4(fe[0] * inv, fe[1] * inv, fe[2] * inv, fe[3] * inv);
      *(float4*)(probs_out + (size_t)t * 8 + 4) =
          make_float4(fe[4] * inv, fe[5] * inv, fe[6] * inv, fe[7] * inv);
      top1_out[t] = inv;  // exp(0)/s
      eid[t] = amax;
    }
  }
  if (ln < 8) chunkHist[chunk * 8 + ln] = hcnt;
  if (ln == 0) {
#pragma unroll
    for (int e = 0; e < NE; ++e) atomicAdd(&probsum[e], psum[e]);
  }
}

// ---------------- scan: exclusive per-expert prefix over 1024 chunks ----------------
__global__ __launch_bounds__(256) void scan_kernel(
    const int* __restrict__ chunkHist, int* __restrict__ chunkBase,
    int* __restrict__ cntkept, const float* __restrict__ probsum,
    float* __restrict__ scalars_out) {
  __shared__ int waveTot[4][NE];
  __shared__ int expTot[NE];
  int tid = threadIdx.x, wv = tid >> 6, ln = tid & 63;
  int h[4][NE];
  int s[NE];
#pragma unroll
  for (int e = 0; e < NE; ++e) s[e] = 0;
#pragma unroll
  for (int c = 0; c < 4; ++c) {
    const int* p = chunkHist + (tid * 4 + c) * 8;
#pragma unroll
    for (int e = 0; e < NE; ++e) { h[c][e] = p[e]; s[e] += h[c][e]; }
  }
  int incl[NE];
#pragma unroll
  for (int e = 0; e < NE; ++e) {
    int v = s[e];
#pragma unroll
    for (int off = 1; off < 64; off <<= 1) {
      int u = __shfl_up(v, off, 64);
      if (ln >= off) v += u;
    }
    incl[e] = v;
  }
  if (ln == 63) {
#pragma unroll
    for (int e = 0; e < NE; ++e) waveTot[wv][e] = incl[e];
  }
  __syncthreads();
  int wofs[NE];
#pragma unroll
  for (int e = 0; e < NE; ++e) wofs[e] = 0;
  for (int w = 0; w < 4; ++w)
    if (w < wv) {
#pragma unroll
      for (int e = 0; e < NE; ++e) wofs[e] += waveTot[w][e];
    }
#pragma unroll
  for (int e = 0; e < NE; ++e) {
    int run = wofs[e] + incl[e] - s[e];
#pragma unroll
    for (int c = 0; c < 4; ++c) {
      chunkBase[(tid * 4 + c) * 8 + e] = run;
      run += h[c][e];
    }
  }
  if (tid == 255) {
#pragma unroll
    for (int e = 0; e < NE; ++e) expTot[e] = wofs[e] + incl[e];
  }
  __syncthreads();
  if (tid == 0) {
    double aux = 0.0;
    float drop = 0.f;
#pragma unroll
    for (int e = 0; e < NE; ++e) {
      int c = expTot[e];
      int k = c > CAP ? CAP : c;
      cntkept[e] = k;
      drop += (float)(c > CAP ? c - CAP : 0);
      aux += ((double)k / 65536.0) * ((double)probsum[e] / 65536.0);
    }
    scalars_out[0] = (float)(8.0 * aux);
    scalars_out[1] = drop;
  }
}

// ---------------- dispatch: ranks, onehot, slot map, zero dropped rows ----------------
__global__ __launch_bounds__(256) void dispatch_kernel(
    const int* __restrict__ eid, const int* __restrict__ chunkBase,
    int* __restrict__ slot2tok, float* __restrict__ onehot_out,
    float* __restrict__ out_main) {
  int tid = threadIdx.x, wv = tid >> 6, ln = tid & 63;
  int chunk = blockIdx.x * 4 + wv;
  int t = chunk * 64 + ln;
  int e = eid[t];
  unsigned long long lower = (1ull << ln) - 1ull;
  int rank = 0;
#pragma unroll
  for (int q = 0; q < NE; ++q) {
    unsigned long long b = __ballot(e == q);
    if (e == q) rank = __popcll(b & lower);
  }
  int pos = chunkBase[chunk * 8 + e] + rank;
  bool kept = pos < CAP;
  float oh[NE];
#pragma unroll
  for (int q = 0; q < NE; ++q) oh[q] = (kept && q == e) ? 1.f : 0.f;
  float4* dst = (float4*)(onehot_out + (size_t)t * 8);
  dst[0] = make_float4(oh[0], oh[1], oh[2], oh[3]);
  dst[1] = make_float4(oh[4], oh[5], oh[6], oh[7]);
  if (kept) {
    slot2tok[e * CAP + pos] = t;
  } else {
    float4 z = make_float4(0.f, 0.f, 0.f, 0.f);
    float4* orow = (float4*)(out_main + (size_t)t * DM);
    for (int i = 0; i < DM / 4; ++i) orow[i] = z;
  }
}

// ---------------- FFN stage 1: H = relu(gather(x) @ Wi^T), bf16 MFMA ----------------
// grid (16, 80, 8); 128x128 tile, BK=32; m97 structure
__global__ __launch_bounds__(256) void ffn1_kernel(
    const unsigned short* __restrict__ xbf, const unsigned short* __restrict__ WiB,
    const int* __restrict__ slot2tok, const int* __restrict__ cntkept,
    unsigned short* __restrict__ H) {
  int e = blockIdx.z;
  int cnt = cntkept[e];
  int m0 = blockIdx.y * 128;
  if (m0 >= cnt) return;
  int n0 = blockIdx.x * 128;
  __shared__ unsigned short As[128 * 32];
  __shared__ unsigned short Bs[128 * 32];
  __shared__ int tokL[128];
  int tid = threadIdx.x;
  if (tid < 128) {
    int slot = m0 + tid;
    tokL[tid] = (slot < cnt) ? slot2tok[e * CAP + slot] : 0;
  }
  __syncthreads();
  int wv = tid >> 6, ln = tid & 63;
  int wm = wv & 1, wn = wv >> 1;
  int rc0 = (wv * 2) * 16 + (ln >> 2);
  int rc1 = rc0 + 16;
  int kb = (ln & 3) * 8;
  const unsigned short* gA0 = xbf + (size_t)tokL[rc0] * DM + kb;
  const unsigned short* gA1 = xbf + (size_t)tokL[rc1] * DM + kb;
  const unsigned short* Bb = WiB + (size_t)e * DFF * DM;
  const unsigned short* gB0 = Bb + (size_t)(n0 + rc0) * DM + kb;
  const unsigned short* gB1 = Bb + (size_t)(n0 + rc1) * DM + kb;
  unsigned short* lA0 = &As[(wv * 2) * 512];
  unsigned short* lA1 = &As[(wv * 2 + 1) * 512];
  unsigned short* lB0 = &Bs[(wv * 2) * 512];
  unsigned short* lB1 = &Bs[(wv * 2 + 1) * 512];
  f32x4 acc[4][4] = {};
  int ar = (wm * 64 + (ln & 15)) * 32 + (ln >> 4) * 8;
  int brr = (wn * 64 + (ln & 15)) * 32 + (ln >> 4) * 8;
  for (int k0 = 0; k0 < DM; k0 += 32) {
    __syncthreads();
    gll16(gA0 + k0, lA0);
    gll16(gA1 + k0, lA1);
    gll16(gB0 + k0, lB0);
    gll16(gB1 + k0, lB1);
    __syncthreads();
    bf16x8 af[4], bf[4];
#pragma unroll
    for (int mt = 0; mt < 4; ++mt) af[mt] = *(const bf16x8*)&As[ar + mt * 16 * 32];
#pragma unroll
    for (int nt = 0; nt < 4; ++nt) bf[nt] = *(const bf16x8*)&Bs[brr + nt * 16 * 32];
#pragma unroll
    for (int mt = 0; mt < 4; ++mt) {
#pragma unroll
      for (int nt = 0; nt < 4; ++nt)
        acc[mt][nt] =
            __builtin_amdgcn_mfma_f32_16x16x32_bf16(af[mt], bf[nt], acc[mt][nt], 0, 0, 0);
    }
  }
  int q4 = (ln >> 4) * 4, cc = ln & 15;
  size_t Hbase = (size_t)e * CAP;
#pragma unroll
  for (int mt = 0; mt < 4; ++mt) {
    int m = m0 + wm * 64 + mt * 16 + q4;
#pragma unroll
    for (int r = 0; r < 4; ++r) {
      unsigned short* hrow = H + (Hbase + m + r) * DFF + n0 + wn * 64 + cc;
#pragma unroll
      for (int nt = 0; nt < 4; ++nt) {
        float v = acc[mt][nt][r];
        v = v > 0.f ? v : 0.f;
        hrow[nt * 16] = f2bf(v);
      }
    }
  }
}

// ---------------- FFN stage 2: out[t] = (H @ Wo^T) * top1_prob[t] ----------------
// grid (4, 80, 8)
__global__ __launch_bounds__(256) void ffn2_kernel(
    const unsigned short* __restrict__ H, const unsigned short* __restrict__ WoB,
    const int* __restrict__ slot2tok, const int* __restrict__ cntkept,
    const float* __restrict__ top1, float* __restrict__ out) {
  int e = blockIdx.z;
  int cnt = cntkept[e];
  int m0 = blockIdx.y * 128;
  if (m0 >= cnt) return;
  int n0 = blockIdx.x * 128;
  __shared__ unsigned short As[128 * 32];
  __shared__ unsigned short Bs[128 * 32];
  __shared__ int tokL[128];
  __shared__ float prL[128];
  int tid = threadIdx.x;
  if (tid < 128) {
    int slot = m0 + tid;
    int t = (slot < cnt) ? slot2tok[e * CAP + slot] : -1;
    tokL[tid] = t;
    prL[tid] = (t >= 0) ? top1[t] : 0.f;
  }
  __syncthreads();
  int wv = tid >> 6, ln = tid & 63;
  int wm = wv & 1, wn = wv >> 1;
  int rc0 = (wv * 2) * 16 + (ln >> 2);
  int rc1 = rc0 + 16;
  int kb = (ln & 3) * 8;
  const unsigned short* gA0 = H + ((size_t)e * CAP + m0 + rc0) * DFF + kb;
  const unsigned short* gA1 = H + ((size_t)e * CAP + m0 + rc1) * DFF + kb;
  const unsigned short* Bb = WoB + (size_t)e * DM * DFF;
  const unsigned short* gB0 = Bb + (size_t)(n0 + rc0) * DFF + kb;
  const unsigned short* gB1 = Bb + (size_t)(n0 + rc1) * DFF + kb;
  unsigned short* lA0 = &As[(wv * 2) * 512];
  unsigned short* lA1 = &As[(wv * 2 + 1) * 512];
  unsigned short* lB0 = &Bs[(wv * 2) * 512];
  unsigned short* lB1 = &Bs[(wv * 2 + 1) * 512];
  f32x4 acc[4][4] = {};
  int ar = (wm * 64 + (ln & 15)) * 32 + (ln >> 4) * 8;
  int brr = (wn * 64 + (ln & 15)) * 32 + (ln >> 4) * 8;
  for (int k0 = 0; k0 < DFF; k0 += 32) {
    __syncthreads();
    gll16(gA0 + k0, lA0);
    gll16(gA1 + k0, lA1);
    gll16(gB0 + k0, lB0);
    gll16(gB1 + k0, lB1);
    __syncthreads();
    bf16x8 af[4], bf[4];
#pragma unroll
    for (int mt = 0; mt < 4; ++mt) af[mt] = *(const bf16x8*)&As[ar + mt * 16 * 32];
#pragma unroll
    for (int nt = 0; nt < 4; ++nt) bf[nt] = *(const bf16x8*)&Bs[brr + nt * 16 * 32];
#pragma unroll
    for (int mt = 0; mt < 4; ++mt) {
#pragma unroll
      for (int nt = 0; nt < 4; ++nt)
        acc[mt][nt] =
            __builtin_amdgcn_mfma_f32_16x16x32_bf16(af[mt], bf[nt], acc[mt][nt], 0, 0, 0);
    }
  }
  int q4 = (ln >> 4) * 4, cc = ln & 15;
#pragma unroll
  for (int mt = 0; mt < 4; ++mt) {
#pragma unroll
    for (int r = 0; r < 4; ++r) {
      int ml = wm * 64 + mt * 16 + q4 + r;
      int t = tokL[ml];
      if (t >= 0) {
        float p = prL[ml];
        float* orow = out + (size_t)t * DM + n0 + wn * 64 + cc;
#pragma unroll
        for (int nt = 0; nt < 4; ++nt) orow[nt * 16] = acc[mt][nt][r] * p;
      }
    }
  }
}

// ---------------- workspace layout (bytes) ----------------
#define OFF_PROBSUM ((size_t)0)          // 32 B, memset to 0
#define OFF_CNTKEPT ((size_t)64)         // 32 B
#define OFF_EID ((size_t)256)            // 256 KB
#define OFF_HIST ((size_t)262400)        // 32 KB
#define OFF_BASE ((size_t)295168)        // 32 KB
#define OFF_S2T ((size_t)327936)         // 320 KB
#define OFF_XBF ((size_t)1048576)        // 64 MB
#define OFF_WIB ((size_t)68157440)       // 16 MB
#define OFF_WOB ((size_t)84934656)       // 16 MB
#define OFF_H ((size_t)101711872)        // 320 MB
#define WS_NEED ((size_t)437256192)

extern "C" void kernel_launch(void* const* d_in, const int* in_sizes, int n_in,
                              void* d_out, int out_size, void* d_ws, size_t ws_size,
                              hipStream_t stream) {
  const float* x = (const float*)d_in[0];
  const float* Wr = (const float*)d_in[1];
  const float* br = (const float*)d_in[2];
  const float* Wi = (const float*)d_in[3];
  const float* Wo = (const float*)d_in[4];
  float* out = (float*)d_out;
  float* onehot_out = out + (size_t)TT * DM;
  float* top1_out = onehot_out + (size_t)TT * NE;
  float* probs_out = top1_out + TT;
  float* scalars_out = probs_out + (size_t)TT * NE;  // [aux_loss, num_dropped]

  if (ws_size < WS_NEED) return;  // loud failure; restructure if this trips
  char* ws = (char*)d_ws;
  float* probsum = (float*)(ws + OFF_PROBSUM);
  int* cntkept = (int*)(ws + OFF_CNTKEPT);
  int* eid = (int*)(ws + OFF_EID);
  int* chunkHist = (int*)(ws + OFF_HIST);
  int* chunkBase = (int*)(ws + OFF_BASE);
  int* slot2tok = (int*)(ws + OFF_S2T);
  unsigned short* xbf = (unsigned short*)(ws + OFF_XBF);
  unsigned short* WiB = (unsigned short*)(ws + OFF_WIB);
  unsigned short* WoB = (unsigned short*)(ws + OFF_WOB);
  unsigned short* Hb = (unsigned short*)(ws + OFF_H);

  hipMemsetAsync(probsum, 0, 32, stream);
  convw_kernel<<<2048, 256, 0, stream>>>(Wi, Wo, WiB, WoB);
  router_kernel<<<NCHUNK / 4, 256, 0, stream>>>(x, Wr, br, probs_out, top1_out, eid,
                                                chunkHist, probsum, xbf);
  scan_kernel<<<1, 256, 0, stream>>>(chunkHist, chunkBase, cntkept, probsum, scalars_out);
  dispatch_kernel<<<NCHUNK / 4, 256, 0, stream>>>(eid, chunkBase, slot2tok, onehot_out, out);
  ffn1_kernel<<<dim3(DFF / 128, CAP / 128, NE), 256, 0, stream>>>(xbf, WiB, slot2tok,
                                                                  cntkept, Hb);
  ffn2_kernel<<<dim3(DM / 128, CAP / 128, NE), 256, 0, stream>>>(Hb, WoB, slot2tok,
                                                                 cntkept, top1_out, out);
}

// Round 2
// 831.271 us; speedup vs baseline: 1.0632x; 1.0632x over previous
//
#include <hip/hip_runtime.h>

#define TT 65536          // tokens
#define DM 512            // d_model
#define DFF 2048          // d_ff
#define NE 8              // experts
#define CAP 10240         // capacity per expert
#define NCHUNK (TT / 64)  // 1024 chunks of 64 tokens

typedef __attribute__((ext_vector_type(8))) short bf16x8;
typedef __attribute__((ext_vector_type(4))) float f32x4;

// RTNE f32 -> bf16 (no NaN inputs in this problem)
__device__ __forceinline__ unsigned short f2bf(float f) {
  unsigned u = __float_as_uint(f);
  unsigned r = (u + 0x7fffu + ((u >> 16) & 1u)) >> 16;
  return (unsigned short)r;
}

__device__ __forceinline__ void gll16(const void* g, void* l) {
  __builtin_amdgcn_global_load_lds((const __attribute__((address_space(1))) void*)g,
                                   (__attribute__((address_space(3))) void*)l, 16, 0, 0);
}

// ---------------- weight conversion: Wi/Wo -> bf16, Wr -> wrT64 (f64, [d][e]) ----------------
__global__ __launch_bounds__(256) void convw_kernel(
    const float* __restrict__ Wi, const float* __restrict__ Wo,
    const float* __restrict__ Wr, const float* __restrict__ br,
    unsigned short* __restrict__ WiB, unsigned short* __restrict__ WoB,
    double* __restrict__ wrT64, double* __restrict__ br64) {
  const int n4 = NE * DFF * DM / 4;
  int gid = blockIdx.x * blockDim.x + threadIdx.x;
  int stride = gridDim.x * blockDim.x;
  for (int i = gid; i < n4; i += stride) {
    float4 a = ((const float4*)Wi)[i];
    ushort4 oa;
    oa.x = f2bf(a.x); oa.y = f2bf(a.y); oa.z = f2bf(a.z); oa.w = f2bf(a.w);
    ((ushort4*)WiB)[i] = oa;
    float4 b = ((const float4*)Wo)[i];
    ushort4 ob;
    ob.x = f2bf(b.x); ob.y = f2bf(b.y); ob.z = f2bf(b.z); ob.w = f2bf(b.w);
    ((ushort4*)WoB)[i] = ob;
  }
  // router weights: transpose [E][D] -> [D][E], promote to f64
  for (int i = gid; i < DM * NE; i += stride) {
    int d = i >> 3, e = i & 7;
    wrT64[i] = (double)Wr[e * DM + d];
  }
  if (gid < NE) br64[gid] = (double)br[gid];
}

// ---------------- router: thread-per-token, f64 logits from SMEM weights ----------------
// grid 256 x 256; no LDS, no per-token shuffles
__global__ __launch_bounds__(256) void router_kernel(
    const float* __restrict__ x, const double* __restrict__ wrT64,
    const double* __restrict__ br64, float* __restrict__ probs_out,
    float* __restrict__ top1_out, int* __restrict__ eid,
    int* __restrict__ chunkHist, float* __restrict__ probsum,
    unsigned short* __restrict__ xbf) {
  int tid = threadIdx.x;
  int t = blockIdx.x * 256 + tid;
  int ln = tid & 63;
  const float4* xr = (const float4*)(x + (size_t)t * DM);
  uint4* xb = (uint4*)(xbf + (size_t)t * DM);

  double acc[NE];
#pragma unroll
  for (int e = 0; e < NE; ++e) acc[e] = br64[e];

#pragma unroll 2
  for (int b = 0; b < 16; ++b) {
    float4 buf[8];
#pragma unroll
    for (int j = 0; j < 8; ++j) buf[j] = xr[b * 8 + j];
    // bf16 copy of x for FFN stage (64 B contiguous per burst per lane)
#pragma unroll
    for (int j = 0; j < 4; ++j) {
      uint4 pk;
      pk.x = (unsigned)f2bf(buf[2 * j].x) | ((unsigned)f2bf(buf[2 * j].y) << 16);
      pk.y = (unsigned)f2bf(buf[2 * j].z) | ((unsigned)f2bf(buf[2 * j].w) << 16);
      pk.z = (unsigned)f2bf(buf[2 * j + 1].x) | ((unsigned)f2bf(buf[2 * j + 1].y) << 16);
      pk.w = (unsigned)f2bf(buf[2 * j + 1].z) | ((unsigned)f2bf(buf[2 * j + 1].w) << 16);
      xb[b * 4 + j] = pk;
    }
#pragma unroll
    for (int j = 0; j < 8; ++j) {
      const double* w = wrT64 + (size_t)(b * 32 + j * 4) * 8;  // uniform -> s_load
      double dx = (double)buf[j].x, dy = (double)buf[j].y;
      double dz = (double)buf[j].z, dw = (double)buf[j].w;
#pragma unroll
      for (int e = 0; e < NE; ++e) acc[e] += dx * w[e];
#pragma unroll
      for (int e = 0; e < NE; ++e) acc[e] += dy * w[8 + e];
#pragma unroll
      for (int e = 0; e < NE; ++e) acc[e] += dz * w[16 + e];
#pragma unroll
      for (int e = 0; e < NE; ++e) acc[e] += dw * w[24 + e];
    }
  }

  // thread-local argmax (first-max on ties, like np.argmax) + softmax
  double best = acc[0];
  int amax = 0;
#pragma unroll
  for (int e = 1; e < NE; ++e)
    if (acc[e] > best) { best = acc[e]; amax = e; }
  float fe[NE];
  float s = 0.f;
#pragma unroll
  for (int e = 0; e < NE; ++e) { fe[e] = expf((float)(acc[e] - best)); s += fe[e]; }
  float inv = 1.0f / s;

  float4 p0 = make_float4(fe[0] * inv, fe[1] * inv, fe[2] * inv, fe[3] * inv);
  float4 p1 = make_float4(fe[4] * inv, fe[5] * inv, fe[6] * inv, fe[7] * inv);
  *(float4*)(probs_out + (size_t)t * 8) = p0;
  *(float4*)(probs_out + (size_t)t * 8 + 4) = p1;
  top1_out[t] = inv;  // fe[amax] == exp(0) == 1
  eid[t] = amax;

  // per-chunk (== per-wave) expert histogram via ballots
  int chunk = t >> 6;
#pragma unroll
  for (int e = 0; e < NE; ++e) {
    unsigned long long bl = __ballot(amax == e);
    if (ln == e) chunkHist[chunk * 8 + e] = __popcll(bl);
  }

  // probs column-sum: butterfly once per wave, one atomic per expert per wave
  float pv[NE] = {p0.x, p0.y, p0.z, p0.w, p1.x, p1.y, p1.z, p1.w};
#pragma unroll
  for (int e = 0; e < NE; ++e) {
#pragma unroll
    for (int off = 32; off > 0; off >>= 1) pv[e] += __shfl_xor(pv[e], off, 64);
  }
  if (ln == 0) {
#pragma unroll
    for (int e = 0; e < NE; ++e) atomicAdd(&probsum[e], pv[e]);
  }
}

// ---------------- scan: exclusive per-expert prefix over 1024 chunks ----------------
__global__ __launch_bounds__(256) void scan_kernel(
    const int* __restrict__ chunkHist, int* __restrict__ chunkBase,
    int* __restrict__ cntkept, const float* __restrict__ probsum,
    float* __restrict__ scalars_out) {
  __shared__ int waveTot[4][NE];
  __shared__ int expTot[NE];
  int tid = threadIdx.x, wv = tid >> 6, ln = tid & 63;
  int h[4][NE];
  int s[NE];
#pragma unroll
  for (int e = 0; e < NE; ++e) s[e] = 0;
#pragma unroll
  for (int c = 0; c < 4; ++c) {
    const int* p = chunkHist + (tid * 4 + c) * 8;
#pragma unroll
    for (int e = 0; e < NE; ++e) { h[c][e] = p[e]; s[e] += h[c][e]; }
  }
  int incl[NE];
#pragma unroll
  for (int e = 0; e < NE; ++e) {
    int v = s[e];
#pragma unroll
    for (int off = 1; off < 64; off <<= 1) {
      int u = __shfl_up(v, off, 64);
      if (ln >= off) v += u;
    }
    incl[e] = v;
  }
  if (ln == 63) {
#pragma unroll
    for (int e = 0; e < NE; ++e) waveTot[wv][e] = incl[e];
  }
  __syncthreads();
  int wofs[NE];
#pragma unroll
  for (int e = 0; e < NE; ++e) wofs[e] = 0;
  for (int w = 0; w < 4; ++w)
    if (w < wv) {
#pragma unroll
      for (int e = 0; e < NE; ++e) wofs[e] += waveTot[w][e];
    }
#pragma unroll
  for (int e = 0; e < NE; ++e) {
    int run = wofs[e] + incl[e] - s[e];
#pragma unroll
    for (int c = 0; c < 4; ++c) {
      chunkBase[(tid * 4 + c) * 8 + e] = run;
      run += h[c][e];
    }
  }
  if (tid == 255) {
#pragma unroll
    for (int e = 0; e < NE; ++e) expTot[e] = wofs[e] + incl[e];
  }
  __syncthreads();
  if (tid == 0) {
    double aux = 0.0;
    float drop = 0.f;
#pragma unroll
    for (int e = 0; e < NE; ++e) {
      int c = expTot[e];
      int k = c > CAP ? CAP : c;
      cntkept[e] = k;
      drop += (float)(c > CAP ? c - CAP : 0);
      aux += ((double)k / 65536.0) * ((double)probsum[e] / 65536.0);
    }
    scalars_out[0] = (float)(8.0 * aux);
    scalars_out[1] = drop;
  }
}

// ---------------- dispatch: ranks, onehot, slot map, zero dropped rows ----------------
__global__ __launch_bounds__(256) void dispatch_kernel(
    const int* __restrict__ eid, const int* __restrict__ chunkBase,
    int* __restrict__ slot2tok, float* __restrict__ onehot_out,
    float* __restrict__ out_main) {
  int tid = threadIdx.x, wv = tid >> 6, ln = tid & 63;
  int chunk = blockIdx.x * 4 + wv;
  int t = chunk * 64 + ln;
  int e = eid[t];
  unsigned long long lower = (1ull << ln) - 1ull;
  int rank = 0;
#pragma unroll
  for (int q = 0; q < NE; ++q) {
    unsigned long long b = __ballot(e == q);
    if (e == q) rank = __popcll(b & lower);
  }
  int pos = chunkBase[chunk * 8 + e] + rank;
  bool kept = pos < CAP;
  float oh[NE];
#pragma unroll
  for (int q = 0; q < NE; ++q) oh[q] = (kept && q == e) ? 1.f : 0.f;
  float4* dst = (float4*)(onehot_out + (size_t)t * 8);
  dst[0] = make_float4(oh[0], oh[1], oh[2], oh[3]);
  dst[1] = make_float4(oh[4], oh[5], oh[6], oh[7]);
  if (kept) {
    slot2tok[e * CAP + pos] = t;
  } else {
    float4 z = make_float4(0.f, 0.f, 0.f, 0.f);
    float4* orow = (float4*)(out_main + (size_t)t * DM);
    for (int i = 0; i < DM / 4; ++i) orow[i] = z;
  }
}

// ---------------- FFN stage 1: H = relu(gather(x) @ Wi^T), bf16 MFMA ----------------
// grid (16, 80, 8); 128x128 tile, BK=32; m97 structure
__global__ __launch_bounds__(256) void ffn1_kernel(
    const unsigned short* __restrict__ xbf, const unsigned short* __restrict__ WiB,
    const int* __restrict__ slot2tok, const int* __restrict__ cntkept,
    unsigned short* __restrict__ H) {
  int e = blockIdx.z;
  int cnt = cntkept[e];
  int m0 = blockIdx.y * 128;
  if (m0 >= cnt) return;
  int n0 = blockIdx.x * 128;
  __shared__ unsigned short As[128 * 32];
  __shared__ unsigned short Bs[128 * 32];
  __shared__ int tokL[128];
  int tid = threadIdx.x;
  if (tid < 128) {
    int slot = m0 + tid;
    tokL[tid] = (slot < cnt) ? slot2tok[e * CAP + slot] : 0;
  }
  __syncthreads();
  int wv = tid >> 6, ln = tid & 63;
  int wm = wv & 1, wn = wv >> 1;
  int rc0 = (wv * 2) * 16 + (ln >> 2);
  int rc1 = rc0 + 16;
  int kb = (ln & 3) * 8;
  const unsigned short* gA0 = xbf + (size_t)tokL[rc0] * DM + kb;
  const unsigned short* gA1 = xbf + (size_t)tokL[rc1] * DM + kb;
  const unsigned short* Bb = WiB + (size_t)e * DFF * DM;
  const unsigned short* gB0 = Bb + (size_t)(n0 + rc0) * DM + kb;
  const unsigned short* gB1 = Bb + (size_t)(n0 + rc1) * DM + kb;
  unsigned short* lA0 = &As[(wv * 2) * 512];
  unsigned short* lA1 = &As[(wv * 2 + 1) * 512];
  unsigned short* lB0 = &Bs[(wv * 2) * 512];
  unsigned short* lB1 = &Bs[(wv * 2 + 1) * 512];
  f32x4 acc[4][4] = {};
  int ar = (wm * 64 + (ln & 15)) * 32 + (ln >> 4) * 8;
  int brr = (wn * 64 + (ln & 15)) * 32 + (ln >> 4) * 8;
  for (int k0 = 0; k0 < DM; k0 += 32) {
    __syncthreads();
    gll16(gA0 + k0, lA0);
    gll16(gA1 + k0, lA1);
    gll16(gB0 + k0, lB0);
    gll16(gB1 + k0, lB1);
    __syncthreads();
    bf16x8 af[4], bf[4];
#pragma unroll
    for (int mt = 0; mt < 4; ++mt) af[mt] = *(const bf16x8*)&As[ar + mt * 16 * 32];
#pragma unroll
    for (int nt = 0; nt < 4; ++nt) bf[nt] = *(const bf16x8*)&Bs[brr + nt * 16 * 32];
#pragma unroll
    for (int mt = 0; mt < 4; ++mt) {
#pragma unroll
      for (int nt = 0; nt < 4; ++nt)
        acc[mt][nt] =
            __builtin_amdgcn_mfma_f32_16x16x32_bf16(af[mt], bf[nt], acc[mt][nt], 0, 0, 0);
    }
  }
  int q4 = (ln >> 4) * 4, cc = ln & 15;
  size_t Hbase = (size_t)e * CAP;
#pragma unroll
  for (int mt = 0; mt < 4; ++mt) {
    int m = m0 + wm * 64 + mt * 16 + q4;
#pragma unroll
    for (int r = 0; r < 4; ++r) {
      unsigned short* hrow = H + (Hbase + m + r) * DFF + n0 + wn * 64 + cc;
#pragma unroll
      for (int nt = 0; nt < 4; ++nt) {
        float v = acc[mt][nt][r];
        v = v > 0.f ? v : 0.f;
        hrow[nt * 16] = f2bf(v);
      }
    }
  }
}

// ---------------- FFN stage 2: out[t] = (H @ Wo^T) * top1_prob[t] ----------------
// grid (4, 80, 8)
__global__ __launch_bounds__(256) void ffn2_kernel(
    const unsigned short* __restrict__ H, const unsigned short* __restrict__ WoB,
    const int* __restrict__ slot2tok, const int* __restrict__ cntkept,
    const float* __restrict__ top1, float* __restrict__ out) {
  int e = blockIdx.z;
  int cnt = cntkept[e];
  int m0 = blockIdx.y * 128;
  if (m0 >= cnt) return;
  int n0 = blockIdx.x * 128;
  __shared__ unsigned short As[128 * 32];
  __shared__ unsigned short Bs[128 * 32];
  __shared__ int tokL[128];
  __shared__ float prL[128];
  int tid = threadIdx.x;
  if (tid < 128) {
    int slot = m0 + tid;
    int t = (slot < cnt) ? slot2tok[e * CAP + slot] : -1;
    tokL[tid] = t;
    prL[tid] = (t >= 0) ? top1[t] : 0.f;
  }
  __syncthreads();
  int wv = tid >> 6, ln = tid & 63;
  int wm = wv & 1, wn = wv >> 1;
  int rc0 = (wv * 2) * 16 + (ln >> 2);
  int rc1 = rc0 + 16;
  int kb = (ln & 3) * 8;
  const unsigned short* gA0 = H + ((size_t)e * CAP + m0 + rc0) * DFF + kb;
  const unsigned short* gA1 = H + ((size_t)e * CAP + m0 + rc1) * DFF + kb;
  const unsigned short* Bb = WoB + (size_t)e * DM * DFF;
  const unsigned short* gB0 = Bb + (size_t)(n0 + rc0) * DFF + kb;
  const unsigned short* gB1 = Bb + (size_t)(n0 + rc1) * DFF + kb;
  unsigned short* lA0 = &As[(wv * 2) * 512];
  unsigned short* lA1 = &As[(wv * 2 + 1) * 512];
  unsigned short* lB0 = &Bs[(wv * 2) * 512];
  unsigned short* lB1 = &Bs[(wv * 2 + 1) * 512];
  f32x4 acc[4][4] = {};
  int ar = (wm * 64 + (ln & 15)) * 32 + (ln >> 4) * 8;
  int brr = (wn * 64 + (ln & 15)) * 32 + (ln >> 4) * 8;
  for (int k0 = 0; k0 < DFF; k0 += 32) {
    __syncthreads();
    gll16(gA0 + k0, lA0);
    gll16(gA1 + k0, lA1);
    gll16(gB0 + k0, lB0);
    gll16(gB1 + k0, lB1);
    __syncthreads();
    bf16x8 af[4], bf[4];
#pragma unroll
    for (int mt = 0; mt < 4; ++mt) af[mt] = *(const bf16x8*)&As[ar + mt * 16 * 32];
#pragma unroll
    for (int nt = 0; nt < 4; ++nt) bf[nt] = *(const bf16x8*)&Bs[brr + nt * 16 * 32];
#pragma unroll
    for (int mt = 0; mt < 4; ++mt) {
#pragma unroll
      for (int nt = 0; nt < 4; ++nt)
        acc[mt][nt] =
            __builtin_amdgcn_mfma_f32_16x16x32_bf16(af[mt], bf[nt], acc[mt][nt], 0, 0, 0);
    }
  }
  int q4 = (ln >> 4) * 4, cc = ln & 15;
#pragma unroll
  for (int mt = 0; mt < 4; ++mt) {
#pragma unroll
    for (int r = 0; r < 4; ++r) {
      int ml = wm * 64 + mt * 16 + q4 + r;
      int t = tokL[ml];
      if (t >= 0) {
        float p = prL[ml];
        float* orow = out + (size_t)t * DM + n0 + wn * 64 + cc;
#pragma unroll
        for (int nt = 0; nt < 4; ++nt) orow[nt * 16] = acc[mt][nt][r] * p;
      }
    }
  }
}

// ---------------- workspace layout (bytes) ----------------
#define OFF_PROBSUM ((size_t)0)          // 32 B, memset to 0
#define OFF_CNTKEPT ((size_t)64)         // 32 B
#define OFF_BR64 ((size_t)128)           // 64 B
#define OFF_EID ((size_t)256)            // 256 KB
#define OFF_HIST ((size_t)262400)        // 32 KB
#define OFF_BASE ((size_t)295168)        // 32 KB
#define OFF_S2T ((size_t)327936)         // 320 KB
#define OFF_WR64 ((size_t)655616)        // 32 KB f64 wrT
#define OFF_XBF ((size_t)1048576)        // 64 MB
#define OFF_WIB ((size_t)68157440)       // 16 MB
#define OFF_WOB ((size_t)84934656)       // 16 MB
#define OFF_H ((size_t)101711872)        // 320 MB
#define WS_NEED ((size_t)437256192)

extern "C" void kernel_launch(void* const* d_in, const int* in_sizes, int n_in,
                              void* d_out, int out_size, void* d_ws, size_t ws_size,
                              hipStream_t stream) {
  const float* x = (const float*)d_in[0];
  const float* Wr = (const float*)d_in[1];
  const float* br = (const float*)d_in[2];
  const float* Wi = (const float*)d_in[3];
  const float* Wo = (const float*)d_in[4];
  float* out = (float*)d_out;
  float* onehot_out = out + (size_t)TT * DM;
  float* top1_out = onehot_out + (size_t)TT * NE;
  float* probs_out = top1_out + TT;
  float* scalars_out = probs_out + (size_t)TT * NE;  // [aux_loss, num_dropped]

  if (ws_size < WS_NEED) return;  // loud failure; restructure if this trips
  char* ws = (char*)d_ws;
  float* probsum = (float*)(ws + OFF_PROBSUM);
  int* cntkept = (int*)(ws + OFF_CNTKEPT);
  double* br64 = (double*)(ws + OFF_BR64);
  int* eid = (int*)(ws + OFF_EID);
  int* chunkHist = (int*)(ws + OFF_HIST);
  int* chunkBase = (int*)(ws + OFF_BASE);
  int* slot2tok = (int*)(ws + OFF_S2T);
  double* wrT64 = (double*)(ws + OFF_WR64);
  unsigned short* xbf = (unsigned short*)(ws + OFF_XBF);
  unsigned short* WiB = (unsigned short*)(ws + OFF_WIB);
  unsigned short* WoB = (unsigned short*)(ws + OFF_WOB);
  unsigned short* Hb = (unsigned short*)(ws + OFF_H);

  hipMemsetAsync(probsum, 0, 32, stream);
  convw_kernel<<<2048, 256, 0, stream>>>(Wi, Wo, Wr, br, WiB, WoB, wrT64, br64);
  router_kernel<<<TT / 256, 256, 0, stream>>>(x, wrT64, br64, probs_out, top1_out, eid,
                                              chunkHist, probsum, xbf);
  scan_kernel<<<1, 256, 0, stream>>>(chunkHist, chunkBase, cntkept, probsum, scalars_out);
  dispatch_kernel<<<NCHUNK / 4, 256, 0, stream>>>(eid, chunkBase, slot2tok, onehot_out, out);
  ffn1_kernel<<<dim3(DFF / 128, CAP / 128, NE), 256, 0, stream>>>(xbf, WiB, slot2tok,
                                                                  cntkept, Hb);
  ffn2_kernel<<<dim3(DM / 128, CAP / 128, NE), 256, 0, stream>>>(Hb, WoB, slot2tok,
                                                                 cntkept, top1_out, out);
}